// Round 1
// baseline (135.809 us; speedup 1.0000x reference)
//
#include <hip/hip_runtime.h>
#include <hip/hip_cooperative_groups.h>
#include <math.h>

namespace cg = cooperative_groups;

#define NTHREADS 256
#define CAP 4096                    // per-batch capacity of compacted arrays
#define NSBLK 544                   // tile-blocks per batch (16x16 upper-tri x 4)
#define NBATCH 2
#define NTILES (NBATCH * NSBLK)     // 1088

// ---- u = diff^2 LUT: float-bit indexed, nearest-midpoint, f32 entries.
#define LUTN 3072
#define OCT_LO (-16)
#define U_MIN 1.52587890625e-5f     // 2^-16
#define U_MAX 255.999f              // just under 2^8
#define IDX_BYTE_BIAS 56832u        // ((127-16)<<7) entries *4B, folded into base

typedef float v2f __attribute__((ext_vector_type(2)));

__device__ __forceinline__ float fsqrt(float x) {
#if __has_builtin(__builtin_amdgcn_sqrtf)
    return __builtin_amdgcn_sqrtf(x);
#else
    return sqrtf(x);
#endif
}
__device__ __forceinline__ float fmed3(float x, float lo, float hi) {
#if __has_builtin(__builtin_amdgcn_fmed3f)
    return __builtin_amdgcn_fmed3f(x, lo, hi);
#else
    return fminf(fmaxf(x, lo), hi);
#endif
}

__device__ __forceinline__ float sig4(float d) {
    const float e = expf(d);
    return 1.0f / (1.0f + e * 0.60653065971263342360f)
         + 1.0f / (1.0f + e * 0.36787944117144232160f)
         + 1.0f / (1.0f + e * 0.13533528323661269189f)
         + 1.0f / (1.0f + e * 0.01831563888873418029f);
}

__device__ __forceinline__ void pair_tail(float sqp, float sqt, float cut2,
                                          const char* __restrict__ lutB,
                                          float& num, float& den) {
    const float r  = fsqrt(sqt * sqp);
    const float u0 = fmaf(-2.0f, r, sqt + sqp);
    const float u  = fmed3(u0, U_MIN, U_MAX);
    const unsigned int bits = __float_as_uint(u);
    const float s  = *(const float*)(lutB + ((bits >> 14) & ~3u));
    const float m  = (sqt < cut2) ? 1.0f : 0.0f;
    num = fmaf(m, s, num);
    den += m;
}

// Single fused cooperative kernel:
//   phase 0: zero tile partials (all blocks) + deterministic compaction
//            (blocks 0..31, no atomics: base = popcount of preceding chunks)
//            + per-block in-LDS LUT build (replaces prep kernel)
//   grid.sync()
//   phase 1: persistent loop over 1088 supertiles (register clamps replace
//            the sentinel pre-fill of C: j>=M / i>=M -> coords 1e9, cuts 0)
//   grid.sync()
//   phase 2: block 0 deterministic final reduce -> out[0]
__global__ __launch_bounds__(NTHREADS) void fused_lddt_kernel(
    const float* __restrict__ pred, const float* __restrict__ tru,
    const int* __restrict__ dna, const int* __restrict__ rna,
    const int* __restrict__ cm,
    float* __restrict__ C, int* __restrict__ Mtot,
    float* __restrict__ pnum, float* __restrict__ pden,
    float* __restrict__ out, int n, int S)
{
    __shared__ __align__(16) float sPX[256], sPY[256], sPZ[256];
    __shared__ __align__(16) float sTX[256], sTY[256], sTZ[256];
    __shared__ __align__(16) float sCut[2 * 256];
    __shared__ __align__(16) float sLUT[LUTN];
    __shared__ float wnum[4], wden[4];
    __shared__ int scanArr[256];
    __shared__ int wsum[4];
    __shared__ double sn0[4], sn1[4], sd0[4], sd1[4];

    const int tid = threadIdx.x;
    const int bid = blockIdx.x;
    const int chunks = n / 256;              // 16
    const int nCompact = NBATCH * chunks;    // 32

    // ---- phase 0a: zero tile partials (so inactive tiles need no writes)
    for (int x = bid * NTHREADS + tid; x < NTILES; x += gridDim.x * NTHREADS) {
        pnum[x] = 0.0f; pden[x] = 0.0f;
    }

    // ---- phase 0b: deterministic compaction (blocks 0..31)
    if (bid < nCompact) {
        const int b = bid / chunks;
        const int chunk = bid - b * chunks;
        const size_t gb = (size_t)b * n;
        const int gi = chunk * 256 + tid;
        const int f = (cm[gb + gi] != 0) ? 1 : 0;

        // base = number of valid atoms in preceding chunks (no atomics,
        // stable original-index order -> deterministic result)
        int pre = 0;
        for (int c = 0; c < chunk; ++c)
            pre += (cm[gb + c * 256 + tid] != 0) ? 1 : 0;
        int v = pre;
        #pragma unroll
        for (int off = 32; off > 0; off >>= 1) v += __shfl_down(v, off, 64);
        if ((tid & 63) == 0) wsum[tid >> 6] = v;
        scanArr[tid] = f;
        __syncthreads();
        const int base = wsum[0] + wsum[1] + wsum[2] + wsum[3];

        #pragma unroll
        for (int off = 1; off < 256; off <<= 1) {   // Hillis-Steele inclusive
            const int a = scanArr[tid];
            const int u = (tid >= off) ? scanArr[tid - off] : 0;
            __syncthreads();
            scanArr[tid] = a + u;
            __syncthreads();
        }
        if (f) {
            const int pos = base + scanArr[tid] - 1;
            const size_t gidx = gb + gi;
            const float* p = pred + gidx * 3;
            const float* tc = tru + gidx * 3;
            const int nt = (dna[gidx] != 0) || (rna[gidx] != 0);
            const int bo = b * CAP;
            C[0 * S + bo + pos] = p[0];  C[1 * S + bo + pos] = p[1];
            C[2 * S + bo + pos] = p[2];  C[3 * S + bo + pos] = tc[0];
            C[4 * S + bo + pos] = tc[1]; C[5 * S + bo + pos] = tc[2];
            C[6 * S + bo + pos] = nt ? 900.0f : 225.0f;
            C[7 * S + bo + pos] = 225.0f;
            C[8 * S + bo + pos] = nt ? 1.0f : 0.0f;
        }
        if (chunk == chunks - 1 && tid == 255) Mtot[b] = base + scanArr[255];
    }

    // ---- phase 0c: build this block's LUT directly in LDS (no prep kernel)
    for (int e = tid; e < LUTN; e += NTHREADS) {
        const int oct = e >> 7;
        const int k   = e & 127;
        const float base2 = exp2f((float)(oct + OCT_LO));
        const float umid = base2 * (1.0f + ((float)k + 0.5f) * 0.0078125f);
        sLUT[e] = sig4(fsqrt(umid));
    }

    cg::this_grid().sync();

    // ---- phase 1: persistent tile loop
    const char* lutB = (const char*)sLUT - IDX_BYTE_BIAS;
    for (int s0 = bid; s0 < NTILES; s0 += gridDim.x) {
        int s = s0;
        const int bi = s / NSBLK;
        s -= bi * NSBLK;
        const int q = s >> 2;
        const int r = s & 3;
        const int W = 33;
        int g = (int)(((float)W - fsqrt((float)(W * W - 8 * q))) * 0.5f);
        while ((g + 1) * 16 - ((g + 1) * g) / 2 <= q) ++g;
        while (g * 16 - (g * (g - 1)) / 2 > q) --g;
        const int sc = g + (q - (g * 16 - (g * (g - 1)) / 2));
        const int ti = 4 * g + r;
        const int i0 = 64 * ti;
        const int J0 = 256 * sc;
        const bool has_diag = (sc == g);
        const int M = Mtot[bi];
        if (i0 >= M || J0 >= M) continue;   // uniform per block; partial stays 0

        const int bo = bi * CAP;
        const float* cpx = C + 0 * S + bo;  const float* cpy = C + 1 * S + bo;
        const float* cpz = C + 2 * S + bo;  const float* ctx = C + 3 * S + bo;
        const float* cty = C + 4 * S + bo;  const float* ctz = C + 5 * S + bo;
        const float* ccn = C + 6 * S + bo;  const float* cco = C + 7 * S + bo;
        const float* cntf = C + 8 * S + bo;

        {   // column staging with register clamp (replaces sentinel pre-fill;
            // sentinel algebra: coords 1e9 -> u0 ~ 0 after clamp, cut 0 -> m=0)
            const int j = J0 + tid;
            const bool jv = j < M;
            sPX[tid] = jv ? cpx[j] : 1.0e9f;
            sPY[tid] = jv ? cpy[j] : 1.0e9f;
            sPZ[tid] = jv ? cpz[j] : 1.0e9f;
            sTX[tid] = jv ? ctx[j] : 1.0e9f;
            sTY[tid] = jv ? cty[j] : 1.0e9f;
            sTZ[tid] = jv ? ctz[j] : 1.0e9f;
            sCut[tid]       = jv ? ccn[j] : 0.0f;
            sCut[256 + tid] = jv ? cco[j] : 0.0f;
        }

        const int w = tid >> 6;
        const int l = tid & 63;
        const int i = i0 + l;
        const bool iv = i < M;
        const float pix = iv ? cpx[i] : 1.0e9f;
        const float piy = iv ? cpy[i] : 1.0e9f;
        const float piz = iv ? cpz[i] : 1.0e9f;
        const float tix = iv ? ctx[i] : 1.0e9f;
        const float tiy = iv ? cty[i] : 1.0e9f;
        const float tiz = iv ? ctz[i] : 1.0e9f;
        const bool nti = iv ? (cntf[i] != 0.0f) : false;
        __syncthreads();

        const float* cutsel = nti ? &sCut[0] : &sCut[256];
        const int kbase = 16 * w;

        const v2f px2 = {pix, pix}, py2 = {piy, piy}, pz2 = {piz, piz};
        const v2f tx2 = {tix, tix}, ty2 = {tiy, tiy}, tz2 = {tiz, tiz};

        float accn = 0.0f, accd = 0.0f;

        #pragma unroll
        for (int c = 0; c < 4; ++c) {
            const int tj = 4 * sc + c;
            if (tj < ti || 64 * tj >= M) continue;
            const bool diag = has_diag && (c == r);
            const int o = 64 * c;

            float num = 0.0f, den = 0.0f;
            #pragma unroll
            for (int qd = 0; qd < 4; ++qd) {
                const int jq = o + kbase + 4 * qd;
                const float4 PX = *(const float4*)&sPX[jq];
                const float4 PY = *(const float4*)&sPY[jq];
                const float4 PZ = *(const float4*)&sPZ[jq];
                const float4 TX = *(const float4*)&sTX[jq];
                const float4 TY = *(const float4*)&sTY[jq];
                const float4 TZ = *(const float4*)&sTZ[jq];
                const float4 CTC = *(const float4*)&cutsel[jq];

                v2f dx, dy, dz, sqpA, sqpB, sqtA, sqtB;

                dx = px2 - (v2f){PX.x, PX.y}; dy = py2 - (v2f){PY.x, PY.y}; dz = pz2 - (v2f){PZ.x, PZ.y};
                sqpA = dx * dx + dy * dy + dz * dz;
                dx = tx2 - (v2f){TX.x, TX.y}; dy = ty2 - (v2f){TY.x, TY.y}; dz = tz2 - (v2f){TZ.x, TZ.y};
                sqtA = dx * dx + dy * dy + dz * dz;

                dx = px2 - (v2f){PX.z, PX.w}; dy = py2 - (v2f){PY.z, PY.w}; dz = pz2 - (v2f){PZ.z, PZ.w};
                sqpB = dx * dx + dy * dy + dz * dz;
                dx = tx2 - (v2f){TX.z, TX.w}; dy = ty2 - (v2f){TY.z, TY.w}; dz = tz2 - (v2f){TZ.z, TZ.w};
                sqtB = dx * dx + dy * dy + dz * dz;

                pair_tail(sqpA.x, sqtA.x, CTC.x, lutB, num, den);
                pair_tail(sqpA.y, sqtA.y, CTC.y, lutB, num, den);
                pair_tail(sqpB.x, sqtB.x, CTC.z, lutB, num, den);
                pair_tail(sqpB.y, sqtB.y, CTC.w, lutB, num, den);
            }
            const float sc2 = diag ? 1.0f : 2.0f;   // symmetry weight
            accn = fmaf(sc2, num, accn);
            accd = fmaf(sc2, den, accd);
        }

        // remove self-pair (added once on diag tile iff lane's chunk holds j=l
        // and the row is a real atom)
        if (has_diag && ((l >> 4) == w) && iv) {
            accn -= sLUT[0];
            accd -= 1.0f;
        }

        #pragma unroll
        for (int off = 32; off > 0; off >>= 1) {
            accn += __shfl_down(accn, off, 64);
            accd += __shfl_down(accd, off, 64);
        }
        if ((tid & 63) == 0) { wnum[w] = accn; wden[w] = accd; }
        __syncthreads();
        if (tid == 0) {
            pnum[s0] = wnum[0] + wnum[1] + wnum[2] + wnum[3];
            pden[s0] = wden[0] + wden[1] + wden[2] + wden[3];
        }
        // no extra sync needed: next iteration's wnum writes are fenced by its
        // own post-staging __syncthreads, ordering them after tid0's reads
    }

    cg::this_grid().sync();

    // ---- phase 2: final deterministic reduce (block 0)
    if (bid == 0) {
        double n0 = 0, n1 = 0, d0 = 0, d1 = 0;
        for (int x = tid; x < NTILES; x += NTHREADS) {
            if (x < NSBLK) { n0 += (double)pnum[x]; d0 += (double)pden[x]; }
            else           { n1 += (double)pnum[x]; d1 += (double)pden[x]; }
        }
        #pragma unroll
        for (int off = 32; off > 0; off >>= 1) {
            n0 += __shfl_down(n0, off, 64); d0 += __shfl_down(d0, off, 64);
            n1 += __shfl_down(n1, off, 64); d1 += __shfl_down(d1, off, 64);
        }
        const int w2 = tid >> 6;
        if ((tid & 63) == 0) { sn0[w2] = n0; sn1[w2] = n1; sd0[w2] = d0; sd1[w2] = d1; }
        __syncthreads();
        if (tid == 0) {
            double N0 = sn0[0] + sn0[1] + sn0[2] + sn0[3];
            double N1 = sn1[0] + sn1[1] + sn1[2] + sn1[3];
            double D0 = sd0[0] + sd0[1] + sd0[2] + sd0[3];
            double D1 = sd1[0] + sd1[1] + sd1[2] + sd1[3];
            D0 = D0 > 1.0 ? D0 : 1.0;
            D1 = D1 > 1.0 ? D1 : 1.0;
            const double l0 = 0.25 * N0 / D0;
            const double l1 = 0.25 * N1 / D1;
            out[0] = (float)(1.0 - 0.5 * (l0 + l1));
        }
    }
}

extern "C" void kernel_launch(void* const* d_in, const int* in_sizes, int n_in,
                              void* d_out, int out_size, void* d_ws, size_t ws_size,
                              hipStream_t stream) {
    const float* pred = (const float*)d_in[0];
    const float* tru  = (const float*)d_in[1];
    const int*   dna  = (const int*)d_in[2];
    const int*   rna  = (const int*)d_in[3];
    const int*   cm   = (const int*)d_in[4];
    float* outp = (float*)d_out;

    const int B = NBATCH;
    int n = in_sizes[2] / B;              // 4096
    int S = B * CAP;                      // 8192

    // ws layout: [C 9*S f32 | pnum NTILES | pden NTILES | Mtot B ints]
    char* p = (char*)d_ws;
    float* C    = (float*)p;              p += (size_t)9 * S * sizeof(float);
    float* pnum = (float*)p;              p += (size_t)NTILES * sizeof(float);
    float* pden = (float*)p;              p += (size_t)NTILES * sizeof(float);
    int*   Mtot = (int*)p;

    // grid sized to guaranteed co-residency (cached host-side queries only —
    // no allocation/sync, safe under graph capture)
    static int s_gridCap = 0;
    if (s_gridCap == 0) {
        int nb = 0;
        if (hipOccupancyMaxActiveBlocksPerMultiprocessor(&nb, fused_lddt_kernel,
                                                         NTHREADS, 0) != hipSuccess || nb < 1)
            nb = 1;
        int dev = 0;
        (void)hipGetDevice(&dev);
        int cus = 0;
        if (hipDeviceGetAttribute(&cus, hipDeviceAttributeMultiprocessorCount,
                                  dev) != hipSuccess || cus <= 0)
            cus = 256;
        s_gridCap = nb * cus;
    }
    int gridBlocks = s_gridCap < NTILES ? s_gridCap : NTILES;
    const int nCompact = B * (n / 256);   // 32 — must have at least this many
    if (gridBlocks < nCompact) gridBlocks = nCompact;

    void* args[] = { &pred, &tru, &dna, &rna, &cm,
                     &C, &Mtot, &pnum, &pden, &outp, &n, &S };
    hipLaunchCooperativeKernel(fused_lddt_kernel, dim3(gridBlocks),
                               dim3(NTHREADS), args, 0, stream);
}

// Round 2
// 93.655 us; speedup vs baseline: 1.4501x; 1.4501x over previous
//
#include <hip/hip_runtime.h>
#include <math.h>

#define NTHREADS 256
#define CAP 4096                    // per-batch capacity of compacted arrays
#define NSBLK 544                   // tile-blocks per batch (16x16 upper-tri x 4)
#define NBATCH 2
#define NTILES (NBATCH * NSBLK)     // 1088

// ---- u = diff^2 LUT: float-bit indexed, nearest-midpoint, f32 entries.
#define LUTN 3072
#define OCT_LO (-16)
#define U_MIN 1.52587890625e-5f     // 2^-16
#define U_MAX 255.999f              // just under 2^8
#define IDX_BYTE_BIAS 56832u        // ((127-16)<<7) entries *4B, folded into base

typedef float v2f __attribute__((ext_vector_type(2)));

__device__ __forceinline__ float fsqrt(float x) {
#if __has_builtin(__builtin_amdgcn_sqrtf)
    return __builtin_amdgcn_sqrtf(x);
#else
    return sqrtf(x);
#endif
}
__device__ __forceinline__ float fmed3(float x, float lo, float hi) {
#if __has_builtin(__builtin_amdgcn_fmed3f)
    return __builtin_amdgcn_fmed3f(x, lo, hi);
#else
    return fminf(fmaxf(x, lo), hi);
#endif
}

__device__ __forceinline__ float sig4(float d) {
    const float e = expf(d);
    return 1.0f / (1.0f + e * 0.60653065971263342360f)
         + 1.0f / (1.0f + e * 0.36787944117144232160f)
         + 1.0f / (1.0f + e * 0.13533528323661269189f)
         + 1.0f / (1.0f + e * 0.01831563888873418029f);
}

__device__ __forceinline__ void pair_tail(float sqp, float sqt, float cut2,
                                          const char* __restrict__ lutB,
                                          float& num, float& den) {
    const float r  = fsqrt(sqt * sqp);
    const float u0 = fmaf(-2.0f, r, sqt + sqp);
    const float u  = fmed3(u0, U_MIN, U_MAX);
    const unsigned int bits = __float_as_uint(u);
    const float s  = *(const float*)(lutB + ((bits >> 14) & ~3u));
    const float m  = (sqt < cut2) ? 1.0f : 0.0f;
    num = fmaf(m, s, num);
    den += m;
}

// ---- kernel 1: deterministic compaction (no atomics) + LUT build + accum zero.
// Replaces the old prep_kernel entirely: no 288KB sentinel fill (tile kernel
// register-clamps instead), no Mcnt zeroing (base = popcount of preceding
// chunks -> deterministic, order-stable).
__global__ __launch_bounds__(256) void compact_kernel(
    const float* __restrict__ pred, const float* __restrict__ tru,
    const int* __restrict__ dna, const int* __restrict__ rna,
    const int* __restrict__ cm,
    float* __restrict__ C, int* __restrict__ Mtot,
    float* __restrict__ gLUT, double* __restrict__ gacc,
    unsigned int* __restrict__ ticket, int n, int S)
{
    __shared__ int scanArr[256];
    __shared__ int wsum[4];
    const int tid = threadIdx.x;
    const int chunks = n / 256;              // 16
    const int b = blockIdx.x / chunks;
    const int chunk = blockIdx.x - b * chunks;

    // LUT build spread over this kernel's 8192 threads (3072 entries)
    const int gid = blockIdx.x * 256 + tid;
    if (gid < LUTN) {
        const int oct = gid >> 7;
        const int k   = gid & 127;
        const float base2 = exp2f((float)(oct + OCT_LO));
        const float umid = base2 * (1.0f + ((float)k + 0.5f) * 0.0078125f);
        gLUT[gid] = sig4(fsqrt(umid));
    }
    if (gid < 4) gacc[gid] = 0.0;            // {N0,D0,N1,D1}
    if (gid == 4) *ticket = 0u;

    const size_t gb = (size_t)b * n;
    const int gi = chunk * 256 + tid;
    const int f = (cm[gb + gi] != 0) ? 1 : 0;

    // base = number of valid atoms in preceding chunks (deterministic)
    int pre = 0;
    for (int c = 0; c < chunk; ++c)
        pre += (cm[gb + c * 256 + tid] != 0) ? 1 : 0;
    int v = pre;
    #pragma unroll
    for (int off = 32; off > 0; off >>= 1) v += __shfl_down(v, off, 64);
    if ((tid & 63) == 0) wsum[tid >> 6] = v;
    scanArr[tid] = f;
    __syncthreads();
    const int base = wsum[0] + wsum[1] + wsum[2] + wsum[3];

    #pragma unroll
    for (int off = 1; off < 256; off <<= 1) {   // Hillis-Steele inclusive scan
        const int a = scanArr[tid];
        const int u = (tid >= off) ? scanArr[tid - off] : 0;
        __syncthreads();
        scanArr[tid] = a + u;
        __syncthreads();
    }
    if (f) {
        const int pos = base + scanArr[tid] - 1;     // coalesced writes
        const size_t gidx = gb + gi;
        const float* p = pred + gidx * 3;
        const float* tc = tru + gidx * 3;
        const int nt = (dna[gidx] != 0) || (rna[gidx] != 0);
        const int bo = b * CAP;
        C[0 * S + bo + pos] = p[0];  C[1 * S + bo + pos] = p[1];
        C[2 * S + bo + pos] = p[2];  C[3 * S + bo + pos] = tc[0];
        C[4 * S + bo + pos] = tc[1]; C[5 * S + bo + pos] = tc[2];
        C[6 * S + bo + pos] = nt ? 900.0f : 225.0f;
        C[7 * S + bo + pos] = 225.0f;
        C[8 * S + bo + pos] = nt ? 1.0f : 0.0f;
    }
    if (chunk == chunks - 1 && tid == 255) Mtot[b] = base + scanArr[255];
}

// ---- kernel 2: tile compute + last-block-ticket final reduce.
// Partials accumulate via device-scope double atomics (order noise ~1e-16 rel
// in double -> float result bit-stable). Last ticket holder reads the four
// accumulators atomically (coherent across XCDs) and writes out[0].
__global__ __launch_bounds__(NTHREADS) void lddt_tile_kernel(
    const float* __restrict__ C, const int* __restrict__ Mptr,
    const float* __restrict__ gLUT,
    double* __restrict__ gacc, unsigned int* __restrict__ ticket,
    float* __restrict__ out, int S, int ntiles)
{
    __shared__ __align__(16) float sPX[256], sPY[256], sPZ[256];
    __shared__ __align__(16) float sTX[256], sTY[256], sTZ[256];
    __shared__ __align__(16) float sCut[2 * 256];
    __shared__ __align__(16) float sLUT[LUTN];
    __shared__ float wnum[4], wden[4];

    const int tid = threadIdx.x;

    int s = blockIdx.x;
    const int bi = s / NSBLK;
    s -= bi * NSBLK;
    const int q = s >> 2;
    const int r = s & 3;
    const int W = 33;
    int g = (int)(((float)W - fsqrt((float)(W * W - 8 * q))) * 0.5f);
    while ((g + 1) * 16 - ((g + 1) * g) / 2 <= q) ++g;
    while (g * 16 - (g * (g - 1)) / 2 > q) --g;
    const int sc = g + (q - (g * 16 - (g * (g - 1)) / 2));
    const int ti = 4 * g + r;
    const int i0 = 64 * ti;
    const int J0 = 256 * sc;
    const bool has_diag = (sc == g);
    const int M = Mptr[bi];
    const bool active = (i0 < M) && (J0 < M);   // block-uniform

    float blockn = 0.0f, blockd = 0.0f;

    if (active) {
        const int bo = bi * CAP;
        const float* cpx = C + 0 * S + bo;  const float* cpy = C + 1 * S + bo;
        const float* cpz = C + 2 * S + bo;  const float* ctx = C + 3 * S + bo;
        const float* cty = C + 4 * S + bo;  const float* ctz = C + 5 * S + bo;
        const float* ccn = C + 6 * S + bo;  const float* cco = C + 7 * S + bo;
        const float* cntf = C + 8 * S + bo;

        {
            const float4* gl4 = (const float4*)gLUT;
            float4* sl4 = (float4*)sLUT;
            #pragma unroll
            for (int e = tid; e < LUTN / 4; e += NTHREADS) sl4[e] = gl4[e];
        }
        {   // column staging with register clamp (replaces sentinel pre-fill;
            // coords 1e9 -> clamped u, cut 0 -> m=0 so fake pairs never count)
            const int j = J0 + tid;
            const bool jv = j < M;
            sPX[tid] = jv ? cpx[j] : 1.0e9f;
            sPY[tid] = jv ? cpy[j] : 1.0e9f;
            sPZ[tid] = jv ? cpz[j] : 1.0e9f;
            sTX[tid] = jv ? ctx[j] : 1.0e9f;
            sTY[tid] = jv ? cty[j] : 1.0e9f;
            sTZ[tid] = jv ? ctz[j] : 1.0e9f;
            sCut[tid]       = jv ? ccn[j] : 0.0f;
            sCut[256 + tid] = jv ? cco[j] : 0.0f;
        }

        const int w = tid >> 6;
        const int l = tid & 63;
        const int i = i0 + l;
        const bool iv = i < M;
        const float pix = iv ? cpx[i] : 1.0e9f;
        const float piy = iv ? cpy[i] : 1.0e9f;
        const float piz = iv ? cpz[i] : 1.0e9f;
        const float tix = iv ? ctx[i] : 1.0e9f;
        const float tiy = iv ? cty[i] : 1.0e9f;
        const float tiz = iv ? ctz[i] : 1.0e9f;
        const bool nti = iv ? (cntf[i] != 0.0f) : false;
        __syncthreads();

        const float* cutsel = nti ? &sCut[0] : &sCut[256];
        const char* lutB = (const char*)sLUT - IDX_BYTE_BIAS;
        const int kbase = 16 * w;

        const v2f px2 = {pix, pix}, py2 = {piy, piy}, pz2 = {piz, piz};
        const v2f tx2 = {tix, tix}, ty2 = {tiy, tiy}, tz2 = {tiz, tiz};

        float accn = 0.0f, accd = 0.0f;

        #pragma unroll
        for (int c = 0; c < 4; ++c) {
            const int tj = 4 * sc + c;
            if (tj < ti || 64 * tj >= M) continue;
            const bool diag = has_diag && (c == r);
            const int o = 64 * c;

            float num = 0.0f, den = 0.0f;
            #pragma unroll
            for (int qd = 0; qd < 4; ++qd) {
                const int jq = o + kbase + 4 * qd;
                const float4 PX = *(const float4*)&sPX[jq];
                const float4 PY = *(const float4*)&sPY[jq];
                const float4 PZ = *(const float4*)&sPZ[jq];
                const float4 TX = *(const float4*)&sTX[jq];
                const float4 TY = *(const float4*)&sTY[jq];
                const float4 TZ = *(const float4*)&sTZ[jq];
                const float4 CTC = *(const float4*)&cutsel[jq];

                v2f dx, dy, dz, sqpA, sqpB, sqtA, sqtB;

                dx = px2 - (v2f){PX.x, PX.y}; dy = py2 - (v2f){PY.x, PY.y}; dz = pz2 - (v2f){PZ.x, PZ.y};
                sqpA = dx * dx + dy * dy + dz * dz;
                dx = tx2 - (v2f){TX.x, TX.y}; dy = ty2 - (v2f){TY.x, TY.y}; dz = tz2 - (v2f){TZ.x, TZ.y};
                sqtA = dx * dx + dy * dy + dz * dz;

                dx = px2 - (v2f){PX.z, PX.w}; dy = py2 - (v2f){PY.z, PY.w}; dz = pz2 - (v2f){PZ.z, PZ.w};
                sqpB = dx * dx + dy * dy + dz * dz;
                dx = tx2 - (v2f){TX.z, TX.w}; dy = ty2 - (v2f){TY.z, TY.w}; dz = tz2 - (v2f){TZ.z, TZ.w};
                sqtB = dx * dx + dy * dy + dz * dz;

                pair_tail(sqpA.x, sqtA.x, CTC.x, lutB, num, den);
                pair_tail(sqpA.y, sqtA.y, CTC.y, lutB, num, den);
                pair_tail(sqpB.x, sqtB.x, CTC.z, lutB, num, den);
                pair_tail(sqpB.y, sqtB.y, CTC.w, lutB, num, den);
            }
            const float sc2 = diag ? 1.0f : 2.0f;   // symmetry weight
            accn = fmaf(sc2, num, accn);
            accd = fmaf(sc2, den, accd);
        }

        // remove self-pair (added once on diag tile iff lane's chunk holds j=l
        // and the row is a real atom)
        if (has_diag && ((l >> 4) == w) && iv) {
            accn -= sLUT[0];
            accd -= 1.0f;
        }

        #pragma unroll
        for (int off = 32; off > 0; off >>= 1) {
            accn += __shfl_down(accn, off, 64);
            accd += __shfl_down(accd, off, 64);
        }
        if ((tid & 63) == 0) { wnum[w] = accn; wden[w] = accd; }
        __syncthreads();
        if (tid == 0) {
            blockn = wnum[0] + wnum[1] + wnum[2] + wnum[3];
            blockd = wden[0] + wden[1] + wden[2] + wden[3];
        }
    }

    // ---- ticket tail: every block participates exactly once
    if (tid == 0) {
        if (blockn != 0.0f || blockd != 0.0f) {
            atomicAdd(&gacc[2 * bi + 0], (double)blockn);
            atomicAdd(&gacc[2 * bi + 1], (double)blockd);
        }
        __threadfence();                         // order gacc adds before ticket
        const unsigned int t = atomicAdd(ticket, 1u);
        if (t == (unsigned int)ntiles - 1u) {    // last block finishes the job
            __threadfence();
            double N0 = atomicAdd(&gacc[0], 0.0);   // atomic read: coherent
            double D0 = atomicAdd(&gacc[1], 0.0);
            double N1 = atomicAdd(&gacc[2], 0.0);
            double D1 = atomicAdd(&gacc[3], 0.0);
            D0 = D0 > 1.0 ? D0 : 1.0;
            D1 = D1 > 1.0 ? D1 : 1.0;
            const double l0 = 0.25 * N0 / D0;
            const double l1 = 0.25 * N1 / D1;
            out[0] = (float)(1.0 - 0.5 * (l0 + l1));
        }
    }
}

extern "C" void kernel_launch(void* const* d_in, const int* in_sizes, int n_in,
                              void* d_out, int out_size, void* d_ws, size_t ws_size,
                              hipStream_t stream) {
    const float* pred = (const float*)d_in[0];
    const float* tru  = (const float*)d_in[1];
    const int*   dna  = (const int*)d_in[2];
    const int*   rna  = (const int*)d_in[3];
    const int*   cm   = (const int*)d_in[4];
    float* outp = (float*)d_out;

    const int B = NBATCH;
    const int n = in_sizes[2] / B;        // 4096
    const int S = B * CAP;                // 8192

    // ws layout: [LUT 3072 f32 | C 9*S f32 | gacc 4 dbl | ticket | Mtot 2 int]
    char* p = (char*)d_ws;
    float*  gLUT   = (float*)p;           p += (size_t)LUTN * sizeof(float);
    float*  C      = (float*)p;           p += (size_t)9 * S * sizeof(float);
    double* gacc   = (double*)p;          p += 4 * sizeof(double);
    unsigned int* ticket = (unsigned int*)p;  p += sizeof(unsigned int);
    p += sizeof(unsigned int);            // pad to 8B
    int*    Mtot   = (int*)p;

    hipLaunchKernelGGL(compact_kernel, dim3(B * (n / 256)), dim3(256), 0, stream,
                       pred, tru, dna, rna, cm, C, Mtot, gLUT, gacc, ticket, n, S);
    hipLaunchKernelGGL(lddt_tile_kernel, dim3(NTILES), dim3(NTHREADS), 0, stream,
                       C, Mtot, gLUT, gacc, ticket, outp, S, NTILES);
}

// Round 3
// 78.577 us; speedup vs baseline: 1.7284x; 1.1919x over previous
//
#include <hip/hip_runtime.h>
#include <math.h>

#define NTHREADS 256
#define CAP 4096                    // per-batch capacity of compacted arrays
#define NSBLK 544                   // tile-blocks per batch (16x16 upper-tri x 4)
#define NBATCH 2
#define NTILES (NBATCH * NSBLK)     // 1088

// ---- u = diff^2 LUT: float-bit indexed, nearest-midpoint, f32 entries.
#define LUTN 3072
#define OCT_LO (-16)
#define U_MIN 1.52587890625e-5f     // 2^-16
#define U_MAX 255.999f              // just under 2^8
#define IDX_BYTE_BIAS 56832u        // ((127-16)<<7) entries *4B, folded into base

typedef float v2f __attribute__((ext_vector_type(2)));

__device__ __forceinline__ float fsqrt(float x) {
#if __has_builtin(__builtin_amdgcn_sqrtf)
    return __builtin_amdgcn_sqrtf(x);
#else
    return sqrtf(x);
#endif
}
__device__ __forceinline__ float fmed3(float x, float lo, float hi) {
#if __has_builtin(__builtin_amdgcn_fmed3f)
    return __builtin_amdgcn_fmed3f(x, lo, hi);
#else
    return fminf(fmaxf(x, lo), hi);
#endif
}

__device__ __forceinline__ float sig4(float d) {
    const float e = expf(d);
    return 1.0f / (1.0f + e * 0.60653065971263342360f)
         + 1.0f / (1.0f + e * 0.36787944117144232160f)
         + 1.0f / (1.0f + e * 0.13533528323661269189f)
         + 1.0f / (1.0f + e * 0.01831563888873418029f);
}

__device__ __forceinline__ void pair_tail(float sqp, float sqt, float cut2,
                                          const char* __restrict__ lutB,
                                          float& num, float& den) {
    const float r  = fsqrt(sqt * sqp);
    const float u0 = fmaf(-2.0f, r, sqt + sqp);
    const float u  = fmed3(u0, U_MIN, U_MAX);
    const unsigned int bits = __float_as_uint(u);
    const float s  = *(const float*)(lutB + ((bits >> 14) & ~3u));
    const float m  = (sqt < cut2) ? 1.0f : 0.0f;
    num = fmaf(m, s, num);
    den += m;
}

// ---- kernel 1: deterministic compaction (no atomics) + LUT build + partial
// zeroing. Replaces the old prep_kernel. Ordering with kernel 2 comes from the
// kernel boundary (cheap driver-level flush) — NOT in-kernel fences, which cost
// an L2 writeback per releasing block on this chip (round-2 lesson: +15 us).
__global__ __launch_bounds__(256) void compact_kernel(
    const float* __restrict__ pred, const float* __restrict__ tru,
    const int* __restrict__ dna, const int* __restrict__ rna,
    const int* __restrict__ cm,
    float* __restrict__ C, int* __restrict__ Mtot,
    float* __restrict__ gLUT, float* __restrict__ pnum,
    float* __restrict__ pden, int n, int S)
{
    __shared__ int scanArr[256];
    __shared__ int wsum[4];
    const int tid = threadIdx.x;
    const int chunks = n / 256;              // 16
    const int b = blockIdx.x / chunks;
    const int chunk = blockIdx.x - b * chunks;

    // LUT build spread over this kernel's 8192 threads (3072 entries)
    const int gid = blockIdx.x * 256 + tid;
    if (gid < LUTN) {
        const int oct = gid >> 7;
        const int k   = gid & 127;
        const float base2 = exp2f((float)(oct + OCT_LO));
        const float umid = base2 * (1.0f + ((float)k + 0.5f) * 0.0078125f);
        gLUT[gid] = sig4(fsqrt(umid));
    }
    // zero tile partials so inactive tile blocks need no writes (8192 >= NTILES)
    if (gid < NTILES) { pnum[gid] = 0.0f; pden[gid] = 0.0f; }

    const size_t gb = (size_t)b * n;
    const int gi = chunk * 256 + tid;
    const int f = (cm[gb + gi] != 0) ? 1 : 0;

    // base = number of valid atoms in preceding chunks (deterministic)
    int pre = 0;
    for (int c = 0; c < chunk; ++c)
        pre += (cm[gb + c * 256 + tid] != 0) ? 1 : 0;
    int v = pre;
    #pragma unroll
    for (int off = 32; off > 0; off >>= 1) v += __shfl_down(v, off, 64);
    if ((tid & 63) == 0) wsum[tid >> 6] = v;
    scanArr[tid] = f;
    __syncthreads();
    const int base = wsum[0] + wsum[1] + wsum[2] + wsum[3];

    #pragma unroll
    for (int off = 1; off < 256; off <<= 1) {   // Hillis-Steele inclusive scan
        const int a = scanArr[tid];
        const int u = (tid >= off) ? scanArr[tid - off] : 0;
        __syncthreads();
        scanArr[tid] = a + u;
        __syncthreads();
    }
    if (f) {
        const int pos = base + scanArr[tid] - 1;     // coalesced writes
        const size_t gidx = gb + gi;
        const float* p = pred + gidx * 3;
        const float* tc = tru + gidx * 3;
        const int nt = (dna[gidx] != 0) || (rna[gidx] != 0);
        const int bo = b * CAP;
        C[0 * S + bo + pos] = p[0];  C[1 * S + bo + pos] = p[1];
        C[2 * S + bo + pos] = p[2];  C[3 * S + bo + pos] = tc[0];
        C[4 * S + bo + pos] = tc[1]; C[5 * S + bo + pos] = tc[2];
        C[6 * S + bo + pos] = nt ? 900.0f : 225.0f;
        C[7 * S + bo + pos] = 225.0f;
        C[8 * S + bo + pos] = nt ? 1.0f : 0.0f;
    }
    if (chunk == chunks - 1 && tid == 255) Mtot[b] = base + scanArr[255];
}

// ---- kernel 2: tile compute, per-block partials, NO global atomics/fences.
__global__ __launch_bounds__(NTHREADS) void lddt_tile_kernel(
    const float* __restrict__ C, const int* __restrict__ Mptr,
    const float* __restrict__ gLUT,
    float* __restrict__ pnum, float* __restrict__ pden, int S)
{
    __shared__ __align__(16) float sPX[256], sPY[256], sPZ[256];
    __shared__ __align__(16) float sTX[256], sTY[256], sTZ[256];
    __shared__ __align__(16) float sCut[2 * 256];
    __shared__ __align__(16) float sLUT[LUTN];
    __shared__ float wnum[4], wden[4];

    const int tid = threadIdx.x;

    int s = blockIdx.x;
    const int bi = s / NSBLK;
    s -= bi * NSBLK;
    const int q = s >> 2;
    const int r = s & 3;
    const int W = 33;
    int g = (int)(((float)W - fsqrt((float)(W * W - 8 * q))) * 0.5f);
    while ((g + 1) * 16 - ((g + 1) * g) / 2 <= q) ++g;
    while (g * 16 - (g * (g - 1)) / 2 > q) --g;
    const int sc = g + (q - (g * 16 - (g * (g - 1)) / 2));
    const int ti = 4 * g + r;
    const int i0 = 64 * ti;
    const int J0 = 256 * sc;
    const bool has_diag = (sc == g);
    const int M = Mptr[bi];

    if (i0 >= M || J0 >= M) return;   // partials pre-zeroed by compact_kernel

    const int bo = bi * CAP;
    const float* cpx = C + 0 * S + bo;  const float* cpy = C + 1 * S + bo;
    const float* cpz = C + 2 * S + bo;  const float* ctx = C + 3 * S + bo;
    const float* cty = C + 4 * S + bo;  const float* ctz = C + 5 * S + bo;
    const float* ccn = C + 6 * S + bo;  const float* cco = C + 7 * S + bo;
    const float* cntf = C + 8 * S + bo;

    {
        const float4* gl4 = (const float4*)gLUT;
        float4* sl4 = (float4*)sLUT;
        #pragma unroll
        for (int e = tid; e < LUTN / 4; e += NTHREADS) sl4[e] = gl4[e];
    }
    {   // column staging with register clamp (no sentinel pre-fill of C;
        // coords 1e9 -> clamped u, cut 0 -> m=0 so fake pairs never count)
        const int j = J0 + tid;
        const bool jv = j < M;
        sPX[tid] = jv ? cpx[j] : 1.0e9f;
        sPY[tid] = jv ? cpy[j] : 1.0e9f;
        sPZ[tid] = jv ? cpz[j] : 1.0e9f;
        sTX[tid] = jv ? ctx[j] : 1.0e9f;
        sTY[tid] = jv ? cty[j] : 1.0e9f;
        sTZ[tid] = jv ? ctz[j] : 1.0e9f;
        sCut[tid]       = jv ? ccn[j] : 0.0f;
        sCut[256 + tid] = jv ? cco[j] : 0.0f;
    }

    const int w = tid >> 6;
    const int l = tid & 63;
    const int i = i0 + l;
    const bool iv = i < M;
    const float pix = iv ? cpx[i] : 1.0e9f;
    const float piy = iv ? cpy[i] : 1.0e9f;
    const float piz = iv ? cpz[i] : 1.0e9f;
    const float tix = iv ? ctx[i] : 1.0e9f;
    const float tiy = iv ? cty[i] : 1.0e9f;
    const float tiz = iv ? ctz[i] : 1.0e9f;
    const bool nti = iv ? (cntf[i] != 0.0f) : false;
    __syncthreads();

    const float* cutsel = nti ? &sCut[0] : &sCut[256];
    const char* lutB = (const char*)sLUT - IDX_BYTE_BIAS;
    const int kbase = 16 * w;

    const v2f px2 = {pix, pix}, py2 = {piy, piy}, pz2 = {piz, piz};
    const v2f tx2 = {tix, tix}, ty2 = {tiy, tiy}, tz2 = {tiz, tiz};

    float accn = 0.0f, accd = 0.0f;

    #pragma unroll
    for (int c = 0; c < 4; ++c) {
        const int tj = 4 * sc + c;
        if (tj < ti || 64 * tj >= M) continue;
        const bool diag = has_diag && (c == r);
        const int o = 64 * c;

        float num = 0.0f, den = 0.0f;
        #pragma unroll
        for (int qd = 0; qd < 4; ++qd) {
            const int jq = o + kbase + 4 * qd;
            const float4 PX = *(const float4*)&sPX[jq];
            const float4 PY = *(const float4*)&sPY[jq];
            const float4 PZ = *(const float4*)&sPZ[jq];
            const float4 TX = *(const float4*)&sTX[jq];
            const float4 TY = *(const float4*)&sTY[jq];
            const float4 TZ = *(const float4*)&sTZ[jq];
            const float4 CTC = *(const float4*)&cutsel[jq];

            v2f dx, dy, dz, sqpA, sqpB, sqtA, sqtB;

            dx = px2 - (v2f){PX.x, PX.y}; dy = py2 - (v2f){PY.x, PY.y}; dz = pz2 - (v2f){PZ.x, PZ.y};
            sqpA = dx * dx + dy * dy + dz * dz;
            dx = tx2 - (v2f){TX.x, TX.y}; dy = ty2 - (v2f){TY.x, TY.y}; dz = tz2 - (v2f){TZ.x, TZ.y};
            sqtA = dx * dx + dy * dy + dz * dz;

            dx = px2 - (v2f){PX.z, PX.w}; dy = py2 - (v2f){PY.z, PY.w}; dz = pz2 - (v2f){PZ.z, PZ.w};
            sqpB = dx * dx + dy * dy + dz * dz;
            dx = tx2 - (v2f){TX.z, TX.w}; dy = ty2 - (v2f){TY.z, TY.w}; dz = tz2 - (v2f){TZ.z, TZ.w};
            sqtB = dx * dx + dy * dy + dz * dz;

            pair_tail(sqpA.x, sqtA.x, CTC.x, lutB, num, den);
            pair_tail(sqpA.y, sqtA.y, CTC.y, lutB, num, den);
            pair_tail(sqpB.x, sqtB.x, CTC.z, lutB, num, den);
            pair_tail(sqpB.y, sqtB.y, CTC.w, lutB, num, den);
        }
        const float sc2 = diag ? 1.0f : 2.0f;   // symmetry weight
        accn = fmaf(sc2, num, accn);
        accd = fmaf(sc2, den, accd);
    }

    // remove self-pair (added once on diag tile iff lane's chunk holds j=l and
    // the row is a real atom)
    if (has_diag && ((l >> 4) == w) && iv) {
        accn -= sLUT[0];
        accd -= 1.0f;
    }

    #pragma unroll
    for (int off = 32; off > 0; off >>= 1) {
        accn += __shfl_down(accn, off, 64);
        accd += __shfl_down(accd, off, 64);
    }
    if ((tid & 63) == 0) { wnum[w] = accn; wden[w] = accd; }
    __syncthreads();

    if (tid == 0) {
        pnum[blockIdx.x] = wnum[0] + wnum[1] + wnum[2] + wnum[3];
        pden[blockIdx.x] = wden[0] + wden[1] + wden[2] + wden[3];
    }
}

// ---- kernel 3: deterministic final reduce (1 block)
__global__ __launch_bounds__(256) void lddt_final_kernel(
    const float* __restrict__ pnum, const float* __restrict__ pden,
    float* __restrict__ out, int nsblk)
{
    __shared__ double sn0[4], sn1[4], sd0[4], sd1[4];
    double n0 = 0, n1 = 0, d0 = 0, d1 = 0;
    for (int s = threadIdx.x; s < 2 * nsblk; s += 256) {
        if (s < nsblk) { n0 += (double)pnum[s]; d0 += (double)pden[s]; }
        else           { n1 += (double)pnum[s]; d1 += (double)pden[s]; }
    }
    #pragma unroll
    for (int off = 32; off > 0; off >>= 1) {
        n0 += __shfl_down(n0, off, 64); d0 += __shfl_down(d0, off, 64);
        n1 += __shfl_down(n1, off, 64); d1 += __shfl_down(d1, off, 64);
    }
    const int w = threadIdx.x >> 6;
    if ((threadIdx.x & 63) == 0) { sn0[w] = n0; sn1[w] = n1; sd0[w] = d0; sd1[w] = d1; }
    __syncthreads();
    if (threadIdx.x == 0) {
        double N0 = sn0[0] + sn0[1] + sn0[2] + sn0[3];
        double N1 = sn1[0] + sn1[1] + sn1[2] + sn1[3];
        double D0 = sd0[0] + sd0[1] + sd0[2] + sd0[3];
        double D1 = sd1[0] + sd1[1] + sd1[2] + sd1[3];
        D0 = D0 > 1.0 ? D0 : 1.0;
        D1 = D1 > 1.0 ? D1 : 1.0;
        const double l0 = 0.25 * N0 / D0;
        const double l1 = 0.25 * N1 / D1;
        out[0] = (float)(1.0 - 0.5 * (l0 + l1));
    }
}

extern "C" void kernel_launch(void* const* d_in, const int* in_sizes, int n_in,
                              void* d_out, int out_size, void* d_ws, size_t ws_size,
                              hipStream_t stream) {
    const float* pred = (const float*)d_in[0];
    const float* tru  = (const float*)d_in[1];
    const int*   dna  = (const int*)d_in[2];
    const int*   rna  = (const int*)d_in[3];
    const int*   cm   = (const int*)d_in[4];
    float* outp = (float*)d_out;

    const int B = NBATCH;
    const int n = in_sizes[2] / B;        // 4096
    const int S = B * CAP;                // 8192

    // ws layout: [LUT 3072 f32 | C 9*S f32 | pnum NTILES | pden NTILES | Mtot 2]
    char* p = (char*)d_ws;
    float* gLUT = (float*)p;              p += (size_t)LUTN * sizeof(float);
    float* C    = (float*)p;              p += (size_t)9 * S * sizeof(float);
    float* pnum = (float*)p;              p += (size_t)NTILES * sizeof(float);
    float* pden = (float*)p;              p += (size_t)NTILES * sizeof(float);
    int*   Mtot = (int*)p;

    hipLaunchKernelGGL(compact_kernel, dim3(B * (n / 256)), dim3(256), 0, stream,
                       pred, tru, dna, rna, cm, C, Mtot, gLUT, pnum, pden, n, S);
    hipLaunchKernelGGL(lddt_tile_kernel, dim3(NTILES), dim3(NTHREADS), 0, stream,
                       C, Mtot, gLUT, pnum, pden, S);
    hipLaunchKernelGGL(lddt_final_kernel, dim3(1), dim3(256), 0, stream,
                       pnum, pden, outp, NSBLK);
}